// Round 1
// baseline (438.872 us; speedup 1.0000x reference)
//
#include <hip/hip_runtime.h>

// Problem constants (match reference): feats [B,C,H,W] f32, rota [H,C,C] f32.
#define B_ 16
#define C_ 256
#define H_ 128
#define W_ 128

// Compact the block-sparse rotation matrix into a [H][C/2] float2 {cos, sin}
// table. rota[h, 2k, 2k] = cos(h*theta_k); rota[h, 2k+1, 2k] = +sin(h*theta_k).
__global__ void build_cs_table(const float* __restrict__ rota,
                               float2* __restrict__ tab) {
    int i = blockIdx.x * blockDim.x + threadIdx.x;   // 0 .. H_*(C_/2)-1
    if (i >= H_ * (C_ / 2)) return;
    int h = i >> 7;          // / (C_/2)
    int k = i & 127;         // % (C_/2)
    const float* p = rota + (size_t)h * C_ * C_ + (size_t)(2 * k) * C_ + (2 * k);
    tab[i] = make_float2(p[0], p[C_]);   // {cos, sin}
}

// Pairwise RoPE rotation. Each thread handles a float4 of w for BOTH channels
// of one pair -> 2x16B loads + 2x16B stores, fully coalesced (w innermost,
// h*w contiguous). USE_TAB=1 reads the compact L2-resident table; USE_TAB=0
// gathers directly from rota_matrix (fallback if ws too small).
template <int USE_TAB>
__global__ __launch_bounds__(256) void rope_rotate(const float* __restrict__ feats,
                                                   const float* __restrict__ cs_src,
                                                   float* __restrict__ out) {
    const int total = B_ * (C_ / 2) * H_ * (W_ / 4);   // 8388608
    const int stride = gridDim.x * blockDim.x;
    for (int i = blockIdx.x * blockDim.x + threadIdx.x; i < total; i += stride) {
        int w4 = i & 31;            // w/4   (5 bits)
        int h  = (i >> 5) & 127;    // h     (7 bits)
        int k  = (i >> 12) & 127;   // pair  (7 bits)
        int b  = i >> 19;           // batch (4 bits)

        float c, s;
        if (USE_TAB) {
            float2 cs = reinterpret_cast<const float2*>(cs_src)[(h << 7) | k];
            c = cs.x; s = cs.y;
        } else {
            const float* p = cs_src + (size_t)h * C_ * C_ + (size_t)(2 * k) * C_ + (2 * k);
            c = p[0]; s = p[C_];
        }

        size_t base_e = (((size_t)(b * C_ + 2 * k) * H_ + h) * W_) + (w4 << 2);
        size_t base_o = base_e + (size_t)H_ * W_;   // odd channel, +H*W floats

        float4 fe = *reinterpret_cast<const float4*>(feats + base_e);
        float4 fo = *reinterpret_cast<const float4*>(feats + base_o);

        float4 oe, oo;
        oe.x = c * fe.x - s * fo.x;  oo.x = s * fe.x + c * fo.x;
        oe.y = c * fe.y - s * fo.y;  oo.y = s * fe.y + c * fo.y;
        oe.z = c * fe.z - s * fo.z;  oo.z = s * fe.z + c * fo.z;
        oe.w = c * fe.w - s * fo.w;  oo.w = s * fe.w + c * fo.w;

        *reinterpret_cast<float4*>(out + base_e) = oe;
        *reinterpret_cast<float4*>(out + base_o) = oo;
    }
}

extern "C" void kernel_launch(void* const* d_in, const int* in_sizes, int n_in,
                              void* d_out, int out_size, void* d_ws, size_t ws_size,
                              hipStream_t stream) {
    const float* feats = (const float*)d_in[0];
    const float* rota  = (const float*)d_in[1];
    float* out = (float*)d_out;

    const size_t tab_bytes = sizeof(float2) * H_ * (C_ / 2);   // 128 KiB
    if (ws_size >= tab_bytes) {
        float2* tab = (float2*)d_ws;
        build_cs_table<<<(H_ * (C_ / 2) + 255) / 256, 256, 0, stream>>>(rota, tab);
        rope_rotate<1><<<2048, 256, 0, stream>>>(feats, (const float*)tab, out);
    } else {
        rope_rotate<0><<<2048, 256, 0, stream>>>(feats, rota, out);
    }
}